// Round 2
// baseline (115.816 us; speedup 1.0000x reference)
//
#include <hip/hip_runtime.h>
#include <hip/hip_bf16.h>

// AttentionHead: B=4, T=4096, D=1024, DA=64, scale = 1/(sqrt(64)*12) = 1/96.
// Pipeline: prep_w (W^T -> bf16, scale folded) -> proj (x@W + b via MFMA, bf16
// q/k row-major + v transposed) -> attn (flash, swapped-QK^T, split-K waves).

#define T_SEQ 4096
#define NBATCH 4

using bf16x8 = __bf16 __attribute__((ext_vector_type(8)));
using f32x16 = float __attribute__((ext_vector_type(16)));
using uint4v = unsigned int __attribute__((ext_vector_type(4)));

// log2(e) / (sqrt(DA) * N_LAYERS): fold softmax scale AND exp->exp2 conversion into q.
static constexpr float QSCALE = 1.4426950408889634f / 96.0f;

// fp32 -> bf16 (round-to-nearest-even), plain bit math (finite inputs only)
__device__ __forceinline__ unsigned short bf1(float v) {
    unsigned u = __builtin_bit_cast(unsigned, v);
    u += 0x7FFFu + ((u >> 16) & 1u);
    return (unsigned short)(u >> 16);
}
__device__ __forceinline__ unsigned pk2(float lo, float hi) {
    return ((unsigned)bf1(hi) << 16) | (unsigned)bf1(lo);
}
// v_permlane32_swap: a' = {a.lo32, b.lo32}, b' = {a.hi32, b.hi32}
__device__ __forceinline__ void pswap(unsigned& a, unsigned& b) {
    asm volatile("v_permlane32_swap_b32 %0, %1" : "+v"(a), "+v"(b));
}
__device__ __forceinline__ f32x16 zero16() {
    f32x16 z;
#pragma unroll
    for (int i = 0; i < 16; ++i) z[i] = 0.0f;
    return z;
}
#define MFMA32(a, b, c) __builtin_amdgcn_mfma_f32_32x32x16_bf16(a, b, c, 0, 0, 0)

// ---------------- kernel 1: W transpose + bf16 + scale fold ----------------
// Wt[m][a][d] = W_m[d][a] (* QSCALE for m==0), flat [192][1024] bf16.
// bias_t[192]: [bq*QSCALE, bk, bv] fp32.
__global__ __launch_bounds__(256) void prep_w(
        const float* __restrict__ Wq, const float* __restrict__ Wk,
        const float* __restrict__ Wv, const float* __restrict__ bq,
        const float* __restrict__ bk, const float* __restrict__ bv,
        unsigned short* __restrict__ Wt, float* __restrict__ bias_t) {
    const int i = blockIdx.x * 256 + threadIdx.x;   // 3*64*1024 total
    const int m = i >> 16;
    const int a = (i >> 10) & 63;
    const int d = i & 1023;
    const float* W = (m == 0) ? Wq : (m == 1) ? Wk : Wv;
    float val = W[d * 64 + a];
    if (m == 0) val *= QSCALE;
    Wt[i] = bf1(val);
    if (i < 192) {
        const int mm = i >> 6, aa = i & 63;
        const float* bb = (mm == 0) ? bq : (mm == 1) ? bk : bv;
        float v = bb[aa];
        if (mm == 0) v *= QSCALE;
        bias_t[i] = v;
    }
}

// ---------------- kernel 2: QKV projection (MFMA bf16) ----------------
// Block: 64 rows, 4 waves = 2 row-halves x 2 col-halves (96 cols each).
// Per wave: 3 acc frags of 32x32. A = x rows (fp32->bf16 in reg), B = Wt rows.
// Stores: qs/ks [B*T][64] bf16 (q pre-scaled), vt transposed [B][64][T] bf16.
__global__ __launch_bounds__(256) void proj_kernel(
        const float* __restrict__ x, const unsigned short* __restrict__ Wt,
        const float* __restrict__ bias_t, unsigned short* __restrict__ qs,
        unsigned short* __restrict__ ks, unsigned short* __restrict__ vt) {
    const int tid = threadIdx.x;
    const int w = tid >> 6, l = tid & 63, g = l >> 5, c32 = l & 31;
    const int wq = w >> 1, wn = w & 1;
    const int rowbase = blockIdx.x * 64 + wq * 32;
    const float* xp = x + (size_t)(rowbase + c32) * 1024 + g * 8;
    const int colg0 = wn * 96 + c32;
    const unsigned short* bp0 = Wt + (size_t)colg0 * 1024 + g * 8;

    f32x16 acc0 = zero16(), acc1 = zero16(), acc2 = zero16();
#pragma unroll 4
    for (int k0 = 0; k0 < 1024; k0 += 16) {
        float4 xa = *(const float4*)(xp + k0);
        float4 xb = *(const float4*)(xp + k0 + 4);
        uint4v ua;
        ua[0] = pk2(xa.x, xa.y); ua[1] = pk2(xa.z, xa.w);
        ua[2] = pk2(xb.x, xb.y); ua[3] = pk2(xb.z, xb.w);
        bf16x8 af = __builtin_bit_cast(bf16x8, ua);
        bf16x8 b0 = *(const bf16x8*)(bp0 + k0);
        bf16x8 b1 = *(const bf16x8*)(bp0 + 32 * 1024 + k0);
        bf16x8 b2 = *(const bf16x8*)(bp0 + 64 * 1024 + k0);
        acc0 = MFMA32(af, b0, acc0);
        acc1 = MFMA32(af, b1, acc1);
        acc2 = MFMA32(af, b2, acc2);
    }
#pragma unroll
    for (int i = 0; i < 3; ++i) {
        const f32x16& a = (i == 0) ? acc0 : (i == 1) ? acc1 : acc2;
        const int cg = colg0 + 32 * i;
        const float bias = bias_t[cg];
        const int mat = cg >> 6, cm = cg & 63;
        if (mat == 2) {
            // v: store transposed vt[b][cm][t], 4 consecutive rows -> 8B store
#pragma unroll
            for (int q4 = 0; q4 < 4; ++q4) {
                const int rowg = rowbase + 8 * q4 + 4 * g;
                const int b = rowg >> 12, t = rowg & (T_SEQ - 1);
                unsigned lo = pk2(a[4 * q4 + 0] + bias, a[4 * q4 + 1] + bias);
                unsigned hi = pk2(a[4 * q4 + 2] + bias, a[4 * q4 + 3] + bias);
                *(uint2*)(vt + (size_t)b * 64 * T_SEQ + (size_t)cm * T_SEQ + t) =
                    make_uint2(lo, hi);
            }
        } else {
            unsigned short* dst = (mat == 0) ? qs : ks;
#pragma unroll
            for (int r = 0; r < 16; ++r) {
                const int rowg = rowbase + (r & 3) + 8 * (r >> 2) + 4 * g;
                dst[(size_t)rowg * 64 + cm] = bf1(a[r] + bias);
            }
        }
    }
}

// ---------------- kernel 3: causal flash attention ----------------
// Block = (batch, 32-row q-tile). 4 waves split 32-key chunks mod 4.
// S^T = mfma(K, Q): lane holds 16 scores (keys) for q-row (lane&31).
// O^T = mfma(V^T, P): lane holds 32 output dims for q-row (lane&31).
__global__ __launch_bounds__(256) void attn_kernel(
        const unsigned short* __restrict__ qs, const unsigned short* __restrict__ ks,
        const unsigned short* __restrict__ vt, float* __restrict__ out) {
    __shared__ float Osh[4][32][65];   // padded: conflict-free
    __shared__ float msh[4][32];
    __shared__ float ssh[4][32];

    const int tid = threadIdx.x;
    const int w = tid >> 6, l = tid & 63, g = l >> 5, c32 = l & 31;
    const int bx = blockIdx.x;
    const int b = bx >> 7;
    const int jt = 127 - (bx & 127);   // big tiles dispatch first
    const int qbase = jt * 32;

    // Q fragments (B-operand of S^T mfma): row-major 16B loads
    const unsigned short* qp =
        qs + ((size_t)b * T_SEQ + qbase + c32) * 64 + g * 8;
    bf16x8 qf[4];
#pragma unroll
    for (int t = 0; t < 4; ++t) qf[t] = *(const bf16x8*)(qp + 16 * t);

    const unsigned short* pK = ks + ((size_t)b * T_SEQ + c32) * 64 + g * 8;
    const unsigned short* pV = vt + (size_t)b * 64 * T_SEQ + (size_t)c32 * T_SEQ + g * 8;

    auto loadKV = [&](bf16x8(&kf)[4], bf16x8(&vf)[4], int c) {
#pragma unroll
        for (int t = 0; t < 4; ++t)
            kf[t] = *(const bf16x8*)(pK + (size_t)c * 2048 + 16 * t);
#pragma unroll
        for (int mf = 0; mf < 2; ++mf)
#pragma unroll
            for (int kx = 0; kx < 2; ++kx)
                vf[mf * 2 + kx] = *(const bf16x8*)(pV + (size_t)mf * 32 * T_SEQ +
                                                   c * 32 + kx * 16);
    };

    float m = -INFINITY, ssum = 0.0f;
    f32x16 o0 = zero16(), o1 = zero16();
    const int nch = (jt >= w) ? ((jt - w) >> 2) + 1 : 0;

    bf16x8 ka[4], va[4], kb[4], vb[4];
    if (nch > 0) loadKV(ka, va, w);

    auto step = [&](bf16x8(&kc)[4], bf16x8(&vc)[4],
                    bf16x8(&kn)[4], bf16x8(&vn)[4], int i) {
        const int c = w + 4 * i;
        if (i + 1 < nch) loadKV(kn, vn, c + 4);   // prefetch next chunk
        f32x16 s = zero16();
#pragma unroll
        for (int t = 0; t < 4; ++t) s = MFMA32(kc[t], qf[t], s);
        if (c == jt) {   // diagonal chunk: causal mask
#pragma unroll
            for (int r = 0; r < 16; ++r) {
                const int kl = (r & 3) + 8 * (r >> 2) + 4 * g;
                if (kl > c32) s[r] = -1e30f;
            }
        }
        float pm = s[0];
#pragma unroll
        for (int r = 1; r < 16; ++r) pm = fmaxf(pm, s[r]);
        pm = fmaxf(pm, __shfl_xor(pm, 32, 64));
        const float mn = fmaxf(m, pm);
        const float alpha = exp2f(m - mn);
        float p[16], ps = 0.0f;
#pragma unroll
        for (int r = 0; r < 16; ++r) { p[r] = exp2f(s[r] - mn); ps += p[r]; }
        ps += __shfl_xor(ps, 32, 64);
        ssum = ssum * alpha + ps;
        m = mn;
#pragma unroll
        for (int r = 0; r < 16; ++r) { o0[r] *= alpha; o1[r] *= alpha; }
        // pack P -> bf16 B-operand frags (keys lane-local via permlane32_swap)
        unsigned c01 = pk2(p[0], p[1]), c23 = pk2(p[2], p[3]);
        unsigned c45 = pk2(p[4], p[5]), c67 = pk2(p[6], p[7]);
        pswap(c01, c45); pswap(c23, c67);
        unsigned c89 = pk2(p[8], p[9]), cab = pk2(p[10], p[11]);
        unsigned ccd = pk2(p[12], p[13]), cef = pk2(p[14], p[15]);
        pswap(c89, ccd); pswap(cab, cef);
        uint4v u0; u0[0] = c01; u0[1] = c23; u0[2] = c45; u0[3] = c67;
        uint4v u1; u1[0] = c89; u1[1] = cab; u1[2] = ccd; u1[3] = cef;
        bf16x8 pb0 = __builtin_bit_cast(bf16x8, u0);
        bf16x8 pb1 = __builtin_bit_cast(bf16x8, u1);
        o0 = MFMA32(vc[0], pb0, o0);
        o0 = MFMA32(vc[1], pb1, o0);
        o1 = MFMA32(vc[2], pb0, o1);
        o1 = MFMA32(vc[3], pb1, o1);
    };

    for (int i = 0; i < nch; i += 2) {   // manual 2x: static reg double-buffer
        step(ka, va, kb, vb, i);
        if (i + 1 < nch) step(kb, vb, ka, va, i + 1);
    }

    // ---- combine 4 wave-partials ----
    if (l < 32) { msh[w][c32] = m; ssh[w][c32] = ssum; }
#pragma unroll
    for (int r = 0; r < 16; ++r) {
        const int dl = (r & 3) + 8 * (r >> 2) + 4 * g;
        Osh[w][c32][dl] = o0[r];
        Osh[w][c32][32 + dl] = o1[r];
    }
    __syncthreads();

    const int qrow = tid >> 3, d0 = (tid & 7) * 8;
    float mw[4], M = -INFINITY;
#pragma unroll
    for (int u = 0; u < 4; ++u) { mw[u] = msh[u][qrow]; M = fmaxf(M, mw[u]); }
    float sc[4], den = 0.0f;
#pragma unroll
    for (int u = 0; u < 4; ++u) { sc[u] = exp2f(mw[u] - M); den += ssh[u][qrow] * sc[u]; }
    const float inv = 1.0f / den;
    float r8[8];
#pragma unroll
    for (int e = 0; e < 8; ++e) r8[e] = 0.0f;
#pragma unroll
    for (int u = 0; u < 4; ++u)
#pragma unroll
        for (int e = 0; e < 8; ++e) r8[e] += Osh[u][qrow][d0 + e] * sc[u];
    float* op = out + ((size_t)b * T_SEQ + qbase + qrow) * 64 + d0;
#pragma unroll
    for (int e = 0; e < 8; ++e) op[e] = r8[e] * inv;
}

// ---------------- launch ----------------
extern "C" void kernel_launch(void* const* d_in, const int* in_sizes, int n_in,
                              void* d_out, int out_size, void* d_ws, size_t ws_size,
                              hipStream_t stream) {
    const float* x  = (const float*)d_in[0];
    const float* Wq = (const float*)d_in[1];
    const float* bq = (const float*)d_in[2];
    const float* Wk = (const float*)d_in[3];
    const float* bk = (const float*)d_in[4];
    const float* Wv = (const float*)d_in[5];
    const float* bv = (const float*)d_in[6];
    float* out = (float*)d_out;

    char* ws = (char*)d_ws;
    unsigned short* Wt     = (unsigned short*)(ws);                 // 384 KB
    float*          bias_t = (float*)(ws + 393216);                 // 768 B
    unsigned short* qsb    = (unsigned short*)(ws + (1u << 20));    // 2 MB
    unsigned short* ksb    = (unsigned short*)(ws + (3u << 20));    // 2 MB
    unsigned short* vtb    = (unsigned short*)(ws + (5u << 20));    // 2 MB

    prep_w<<<768, 256, 0, stream>>>(Wq, Wk, Wv, bq, bk, bv, Wt, bias_t);
    proj_kernel<<<256, 256, 0, stream>>>(x, Wt, bias_t, qsb, ksb, vtb);
    attn_kernel<<<NBATCH * 128, 256, 0, stream>>>(qsb, ksb, vtb, out);
}

// Round 3
// 113.616 us; speedup vs baseline: 1.0194x; 1.0194x over previous
//
#include <hip/hip_runtime.h>
#include <hip/hip_bf16.h>

// AttentionHead: B=4, T=4096, D=1024, DA=64, scale = 1/(sqrt(64)*12) = 1/96.
// prep_w (LDS-transposed W->bf16) -> proj (512 blk x 6 waves MFMA) ->
// attn (512 blk x 8 waves, keys mod 8, defer-max, cvt_pk pack, LDS combine).

#define T_SEQ 4096

using bf16x8 = __bf16 __attribute__((ext_vector_type(8)));
using f32x16 = float __attribute__((ext_vector_type(16)));
using uint4v = unsigned int __attribute__((ext_vector_type(4)));

// log2(e) / (sqrt(DA) * N_LAYERS): fold softmax scale AND exp->exp2 into q.
static constexpr float QSCALE = 1.4426950408889634f / 96.0f;

// fp32 -> bf16 (RNE) bit math (finite inputs only)
__device__ __forceinline__ unsigned short bf1(float v) {
    unsigned u = __builtin_bit_cast(unsigned, v);
    u += 0x7FFFu + ((u >> 16) & 1u);
    return (unsigned short)(u >> 16);
}
// packed fp32x2 -> bf16x2, single HW instr (dst.lo = lo, dst.hi = hi)
__device__ __forceinline__ unsigned cvt2(float lo, float hi) {
    unsigned r;
    asm("v_cvt_pk_bf16_f32 %0, %1, %2" : "=v"(r) : "v"(lo), "v"(hi));
    return r;
}
// v_permlane32_swap: a' = {a.lo32, b.lo32}, b' = {a.hi32, b.hi32}
__device__ __forceinline__ void pswap(unsigned& a, unsigned& b) {
    asm volatile("v_permlane32_swap_b32 %0, %1" : "+v"(a), "+v"(b));
}
__device__ __forceinline__ f32x16 zero16() {
    f32x16 z;
#pragma unroll
    for (int i = 0; i < 16; ++i) z[i] = 0.0f;
    return z;
}
#define MFMA32(a, b, c) __builtin_amdgcn_mfma_f32_32x32x16_bf16(a, b, c, 0, 0, 0)

// ---------------- kernel 1: W transpose via LDS (coalesced both sides) ----
// 48 blocks: m = bx>>4 (q,k,v), d-tile = bx&15. Wt[m][a][d], bias_t[192].
__global__ __launch_bounds__(256) void prep_w(
        const float* __restrict__ Wq, const float* __restrict__ Wk,
        const float* __restrict__ Wv, const float* __restrict__ bq,
        const float* __restrict__ bk, const float* __restrict__ bv,
        unsigned short* __restrict__ Wt, float* __restrict__ bias_t) {
    __shared__ float tile[64][65];
    const int tid = threadIdx.x;
    const int m = blockIdx.x >> 4, d0 = (blockIdx.x & 15) * 64;
    const float* W = (m == 0) ? Wq : (m == 1) ? Wk : Wv;
    const int a = tid & 63, r4 = tid >> 6;
#pragma unroll
    for (int j = 0; j < 16; ++j) {
        const int rr = r4 + 4 * j;
        tile[rr][a] = W[(size_t)(d0 + rr) * 64 + a];   // coalesced 256B
    }
    __syncthreads();
    const float scl = (m == 0) ? QSCALE : 1.0f;
    const int dc = tid & 63, ar = tid >> 6;
#pragma unroll
    for (int j = 0; j < 16; ++j) {
        const int aa = ar + 4 * j;
        Wt[(size_t)m * 65536 + (size_t)aa * 1024 + d0 + dc] =
            bf1(tile[dc][aa] * scl);                   // coalesced 128B
    }
    if ((blockIdx.x & 15) == 0 && tid < 64) {
        const float* bb = (m == 0) ? bq : (m == 1) ? bk : bv;
        bias_t[m * 64 + tid] = bb[tid] * scl;
    }
}

// ---------------- kernel 2: QKV projection ----------------
// 512 blocks x 384 thr: 32 rows/block, wave w -> col-tile w (32 of 192 cols).
__global__ __launch_bounds__(384) void proj_kernel(
        const float* __restrict__ x, const unsigned short* __restrict__ Wt,
        const float* __restrict__ bias_t, unsigned short* __restrict__ qs,
        unsigned short* __restrict__ ks, unsigned short* __restrict__ vt) {
    const int tid = threadIdx.x;
    const int w = tid >> 6, l = tid & 63, g = l >> 5, c32 = l & 31;
    const int rowbase = blockIdx.x * 32;
    const float* xp = x + (size_t)(rowbase + c32) * 1024 + g * 8;
    const unsigned short* bp = Wt + (size_t)(w * 32 + c32) * 1024 + g * 8;

    f32x16 acc = zero16();
#pragma unroll 4
    for (int k0 = 0; k0 < 1024; k0 += 16) {
        float4 xa = *(const float4*)(xp + k0);
        float4 xb = *(const float4*)(xp + k0 + 4);
        uint4v ua;
        ua[0] = cvt2(xa.x, xa.y); ua[1] = cvt2(xa.z, xa.w);
        ua[2] = cvt2(xb.x, xb.y); ua[3] = cvt2(xb.z, xb.w);
        bf16x8 af = __builtin_bit_cast(bf16x8, ua);
        bf16x8 bfr = *(const bf16x8*)(bp + k0);
        acc = MFMA32(af, bfr, acc);
    }
    const int cg = w * 32 + c32;
    const float bias = bias_t[cg];
    const int mat = cg >> 6, cm = cg & 63;
    if (mat == 2) {
        // v transposed: vt[b][cm][t], 4 consecutive rows -> 8B store
#pragma unroll
        for (int q4 = 0; q4 < 4; ++q4) {
            const int rowg = rowbase + 8 * q4 + 4 * g;
            const int b = rowg >> 12, t = rowg & (T_SEQ - 1);
            unsigned lo = cvt2(acc[4 * q4 + 0] + bias, acc[4 * q4 + 1] + bias);
            unsigned hi = cvt2(acc[4 * q4 + 2] + bias, acc[4 * q4 + 3] + bias);
            *(uint2*)(vt + (size_t)b * 64 * T_SEQ + (size_t)cm * T_SEQ + t) =
                make_uint2(lo, hi);
        }
    } else {
        unsigned short* dst = (mat == 0) ? qs : ks;
#pragma unroll
        for (int r = 0; r < 16; ++r) {
            const int rowg = rowbase + (r & 3) + 8 * (r >> 2) + 4 * g;
            dst[(size_t)rowg * 64 + cm] = bf1(acc[r] + bias);
        }
    }
}

// ---------------- kernel 3: causal flash attention ----------------
// Block = one 32-row q-tile. 8 waves split 32-key chunks mod 8.
// S^T = mfma(K, Q); O^T = mfma(V^T, P). Defer-max (THR=8 in exp2 units).
__global__ __launch_bounds__(512) void attn_kernel(
        const unsigned short* __restrict__ qs, const unsigned short* __restrict__ ks,
        const unsigned short* __restrict__ vt, float* __restrict__ out) {
    __shared__ float Osh[8][32][66];
    __shared__ float msh[8][32];
    __shared__ float ssh[8][32];

    const int tid = threadIdx.x;
    const int w = tid >> 6, l = tid & 63, g = l >> 5, c32 = l & 31;
    const int b = blockIdx.x & 3;
    const int jt = 127 - (blockIdx.x >> 2);   // big tiles first, batches interleaved
    const int qbase = jt * 32;

    const unsigned short* qp =
        qs + ((size_t)b * T_SEQ + qbase + c32) * 64 + g * 8;
    bf16x8 qf[4];
#pragma unroll
    for (int t = 0; t < 4; ++t) qf[t] = *(const bf16x8*)(qp + 16 * t);

    // per-wave chunk pointers, advanced by += (no per-chunk 64b addr math)
    const unsigned short* pKc =
        ks + ((size_t)b * T_SEQ + c32) * 64 + g * 8 + (size_t)w * 2048;
    const unsigned short* pVc =
        vt + (size_t)b * 64 * T_SEQ + (size_t)c32 * T_SEQ + g * 8 + w * 32;

    auto loadKV = [&](bf16x8(&kf)[4], bf16x8(&vf)[4]) {
#pragma unroll
        for (int t = 0; t < 4; ++t)
            kf[t] = *(const bf16x8*)(pKc + 16 * t);
#pragma unroll
        for (int mf = 0; mf < 2; ++mf)
#pragma unroll
            for (int kx = 0; kx < 2; ++kx)
                vf[mf * 2 + kx] =
                    *(const bf16x8*)(pVc + (size_t)mf * 32 * T_SEQ + kx * 16);
        pKc += 8 * 2048;   // 8 chunks ahead (wave-strided)
        pVc += 8 * 32;
    };

    float m = -INFINITY, ssum = 0.0f;
    f32x16 o0 = zero16(), o1 = zero16();
    const int nch = (jt >= w) ? ((jt - w) >> 3) + 1 : 0;

    bf16x8 ka[4], va[4], kb[4], vb[4];
    if (nch > 0) loadKV(ka, va);

    auto step = [&](bf16x8(&kc)[4], bf16x8(&vc)[4],
                    bf16x8(&kn)[4], bf16x8(&vn)[4], int i) {
        const int c = w + 8 * i;
        if (i + 1 < nch) loadKV(kn, vn);   // prefetch next chunk
        f32x16 s = zero16();
#pragma unroll
        for (int t = 0; t < 4; ++t) s = MFMA32(kc[t], qf[t], s);
        if (c == jt) {   // diagonal chunk: causal mask
#pragma unroll
            for (int r = 0; r < 16; ++r) {
                const int kl = (r & 3) + 8 * (r >> 2) + 4 * g;
                if (kl > c32) s[r] = -1e30f;
            }
        }
        float pm = s[0];
#pragma unroll
        for (int r = 1; r < 16; ++r) pm = fmaxf(pm, s[r]);
        pm = fmaxf(pm, __shfl_xor(pm, 32, 64));
        if (!__all(pm <= m + 8.0f)) {      // defer-max: rescale only on growth
            const float mn = fmaxf(m, pm);
            const float alpha = exp2f(m - mn);
#pragma unroll
            for (int r = 0; r < 16; ++r) { o0[r] *= alpha; o1[r] *= alpha; }
            ssum *= alpha;
            m = mn;
        }
        float p[16], ps = 0.0f;
#pragma unroll
        for (int r = 0; r < 16; ++r) { p[r] = exp2f(s[r] - m); ps += p[r]; }
        ps += __shfl_xor(ps, 32, 64);
        ssum += ps;
        // pack P -> bf16 B-operand frags (keys lane-local via permlane32_swap)
        unsigned c01 = cvt2(p[0], p[1]), c23 = cvt2(p[2], p[3]);
        unsigned c45 = cvt2(p[4], p[5]), c67 = cvt2(p[6], p[7]);
        pswap(c01, c45); pswap(c23, c67);
        unsigned c89 = cvt2(p[8], p[9]), cab = cvt2(p[10], p[11]);
        unsigned ccd = cvt2(p[12], p[13]), cef = cvt2(p[14], p[15]);
        pswap(c89, ccd); pswap(cab, cef);
        uint4v u0; u0[0] = c01; u0[1] = c23; u0[2] = c45; u0[3] = c67;
        uint4v u1; u1[0] = c89; u1[1] = cab; u1[2] = ccd; u1[3] = cef;
        bf16x8 pb0 = __builtin_bit_cast(bf16x8, u0);
        bf16x8 pb1 = __builtin_bit_cast(bf16x8, u1);
        o0 = MFMA32(vc[0], pb0, o0);
        o0 = MFMA32(vc[1], pb1, o0);
        o1 = MFMA32(vc[2], pb0, o1);
        o1 = MFMA32(vc[3], pb1, o1);
    };

    for (int i = 0; i < nch; i += 2) {   // static reg double-buffer
        step(ka, va, kb, vb, i);
        if (i + 1 < nch) step(kb, vb, ka, va, i + 1);
    }

    // ---- combine 8 wave-partials ----
    if (l < 32) { msh[w][l] = m; ssh[w][l] = ssum; }
#pragma unroll
    for (int r = 0; r < 16; ++r) {
        const int dl = (r & 3) + 8 * (r >> 2) + 4 * g;
        Osh[w][c32][dl] = o0[r];
        Osh[w][c32][32 + dl] = o1[r];
    }
    __syncthreads();

    const int qrow = tid >> 4, d0 = (tid & 15) * 4;
    float mw[8], M = -INFINITY;
#pragma unroll
    for (int u = 0; u < 8; ++u) { mw[u] = msh[u][qrow]; M = fmaxf(M, mw[u]); }
    float den = 0.0f, sc[8];
#pragma unroll
    for (int u = 0; u < 8; ++u) { sc[u] = exp2f(mw[u] - M); den += ssh[u][qrow] * sc[u]; }
    const float inv = 1.0f / den;
    float r4[4] = {0.f, 0.f, 0.f, 0.f};
#pragma unroll
    for (int u = 0; u < 8; ++u)
#pragma unroll
        for (int e = 0; e < 4; ++e) r4[e] += Osh[u][qrow][d0 + e] * sc[u];
    float4 o;
    o.x = r4[0] * inv; o.y = r4[1] * inv; o.z = r4[2] * inv; o.w = r4[3] * inv;
    *(float4*)(out + ((size_t)b * T_SEQ + qbase + qrow) * 64 + d0) = o;
}

// ---------------- launch ----------------
extern "C" void kernel_launch(void* const* d_in, const int* in_sizes, int n_in,
                              void* d_out, int out_size, void* d_ws, size_t ws_size,
                              hipStream_t stream) {
    const float* x  = (const float*)d_in[0];
    const float* Wq = (const float*)d_in[1];
    const float* bq = (const float*)d_in[2];
    const float* Wk = (const float*)d_in[3];
    const float* bk = (const float*)d_in[4];
    const float* Wv = (const float*)d_in[5];
    const float* bv = (const float*)d_in[6];
    float* out = (float*)d_out;

    char* ws = (char*)d_ws;
    unsigned short* Wt     = (unsigned short*)(ws);                 // 384 KB
    float*          bias_t = (float*)(ws + 393216);                 // 768 B
    unsigned short* qsb    = (unsigned short*)(ws + (1u << 20));    // 2 MB
    unsigned short* ksb    = (unsigned short*)(ws + (3u << 20));    // 2 MB
    unsigned short* vtb    = (unsigned short*)(ws + (5u << 20));    // 2 MB

    prep_w<<<48, 256, 0, stream>>>(Wq, Wk, Wv, bq, bk, bv, Wt, bias_t);
    proj_kernel<<<512, 384, 0, stream>>>(x, Wt, bias_t, qsb, ksb, vtb);
    attn_kernel<<<512, 512, 0, stream>>>(qsb, ksb, vtb, out);
}

// Round 4
// 76.541 us; speedup vs baseline: 1.5131x; 1.4844x over previous
//
#include <hip/hip_runtime.h>
#include <hip/hip_bf16.h>

// AttentionHead: B=4, T=4096, D=1024, DA=64, scale = 1/96 folded into q.
// prep_w (W -> K-chunked bf16 Wt2) -> proj (LDS-staged MFMA GEMM, 12 waves,
// K-split) -> attn (8-wave split-K flash, chunk-tiled V, balanced q-tiles).

#define T_SEQ 4096

using bf16x8 = __bf16 __attribute__((ext_vector_type(8)));
using f32x16 = float __attribute__((ext_vector_type(16)));
using uint4v = unsigned int __attribute__((ext_vector_type(4)));

// log2(e) / (sqrt(DA) * N_LAYERS): fold softmax scale AND exp->exp2 into q.
static constexpr float QSCALE = 1.4426950408889634f / 96.0f;

// fp32 -> bf16 (RNE) bit math (finite inputs only)
__device__ __forceinline__ unsigned short bf1(float v) {
    unsigned u = __builtin_bit_cast(unsigned, v);
    u += 0x7FFFu + ((u >> 16) & 1u);
    return (unsigned short)(u >> 16);
}
// packed fp32x2 -> bf16x2, single HW instr
__device__ __forceinline__ unsigned cvt2(float lo, float hi) {
    unsigned r;
    asm("v_cvt_pk_bf16_f32 %0, %1, %2" : "=v"(r) : "v"(lo), "v"(hi));
    return r;
}
// v_permlane32_swap: a' = {a.lo32, b.lo32}, b' = {a.hi32, b.hi32}
__device__ __forceinline__ void pswap(unsigned& a, unsigned& b) {
    asm volatile("v_permlane32_swap_b32 %0, %1" : "+v"(a), "+v"(b));
}
__device__ __forceinline__ f32x16 zero16() {
    f32x16 z;
#pragma unroll
    for (int i = 0; i < 16; ++i) z[i] = 0.0f;
    return z;
}
#define MFMA32(a, b, c) __builtin_amdgcn_mfma_f32_32x32x16_bf16(a, b, c, 0, 0, 0)

// ---------------- kernel 1: W -> Wt2[kstep16][192 cols][64 k] bf16 ---------
// 48 blocks: m = bx>>4 (q,k,v), k-tile = bx&15. bias_t[192] fp32.
__global__ __launch_bounds__(256) void prep_w(
        const float* __restrict__ Wq, const float* __restrict__ Wk,
        const float* __restrict__ Wv, const float* __restrict__ bq,
        const float* __restrict__ bk, const float* __restrict__ bv,
        unsigned short* __restrict__ Wt2, float* __restrict__ bias_t) {
    __shared__ float tile[64][65];
    const int tid = threadIdx.x;
    const int m = blockIdx.x >> 4, kt = blockIdx.x & 15, d0 = kt * 64;
    const float* W = (m == 0) ? Wq : (m == 1) ? Wk : Wv;
    const int a = tid & 63, r4 = tid >> 6;
#pragma unroll
    for (int j = 0; j < 16; ++j) {
        const int rr = r4 + 4 * j;
        tile[rr][a] = W[(size_t)(d0 + rr) * 64 + a];   // coalesced 256B
    }
    __syncthreads();
    const float scl = (m == 0) ? QSCALE : 1.0f;
    const int dc = tid & 63, ar = tid >> 6;
#pragma unroll
    for (int j = 0; j < 16; ++j) {
        const int aa = ar + 4 * j;
        Wt2[(size_t)kt * 12288 + (size_t)(m * 64 + aa) * 64 + dc] =
            bf1(tile[dc][aa] * scl);                   // coalesced 128B
    }
    if (kt == 0 && tid < 64) {
        const float* bb = (m == 0) ? bq : (m == 1) ? bk : bv;
        bias_t[m * 64 + tid] = bb[tid] * scl;
    }
}

// ---------------- kernel 2: QKV projection (LDS-staged MFMA GEMM) ----------
// 512 blocks x 768 thr = 12 waves: wave = (ct 0..5, kh 0..1). 32 rows/block.
// A (x rows) staged coalesced f32 -> bf16 -> XOR-swizzled LDS, double-buffered.
// B = Wt2 K-chunk (contiguous 4KB per (ct,kstep)). K-halves combine via LDS.
__global__ __launch_bounds__(768) void proj_kernel(
        const float* __restrict__ x, const unsigned short* __restrict__ Wt2,
        const float* __restrict__ bias_t, unsigned short* __restrict__ qs,
        unsigned short* __restrict__ ks, unsigned short* __restrict__ vt) {
    __shared__ unsigned short Ald[2][2][2048];   // [kh][buf][32 rows x 64 k]
    __shared__ float Osum[6][64][16];            // kh=1 partials

    const int tid = threadIdx.x;
    const int w = tid >> 6, l = tid & 63, g = l >> 5, c32 = l & 31;
    const int ct = w >> 1, kh = w & 1;
    const int rowbase = blockIdx.x * 32;

    // staging: 512 float4 loads per kh-group (384 thr: si<128 do two)
    const int si = ct * 64 + l;
    const int r0 = si >> 4, k40 = si & 15;
    const int i1 = si + 384, r1 = i1 >> 4, k41 = i1 & 15;
    const float* xb0 = x + (size_t)(rowbase + r0) * 1024 + kh * 512 + k40 * 4;
    const float* xb1 = x + (size_t)(rowbase + r1) * 1024 + kh * 512 + k41 * 4;
    const int wo0 = r0 * 64 + (((k40 >> 1) ^ (r0 & 7)) << 3) + (k40 & 1) * 4;
    const int wo1 = r1 * 64 + (((k41 >> 1) ^ (r1 & 7)) << 3) + (k41 & 1) * 4;

    // B pointer: Wt2[kstep][192][64], kstep = kh*8 + kt
    const unsigned short* Wb =
        Wt2 + (size_t)(kh * 8) * 12288 + (size_t)(ct * 32 + c32) * 64 + g * 8;
    const int aro = c32 * 64;            // A-frag row base (ushorts)
    const int as = c32 & 7;              // swizzle key

    f32x16 acc = zero16();

    // prologue: stage kt=0 into buf 0
    {
        float4 a = *(const float4*)(xb0);
        float4 b4;
        if (si < 128) b4 = *(const float4*)(xb1);
        *(uint2*)(Ald[kh][0] + wo0) = make_uint2(cvt2(a.x, a.y), cvt2(a.z, a.w));
        if (si < 128)
            *(uint2*)(Ald[kh][0] + wo1) = make_uint2(cvt2(b4.x, b4.y), cvt2(b4.z, b4.w));
    }
    __syncthreads();

    int buf = 0;
#pragma unroll
    for (int kt = 0; kt < 8; ++kt) {
        float4 a, b4;
        if (kt < 7) {                     // issue next-step loads early
            a = *(const float4*)(xb0 + (kt + 1) * 64);
            if (si < 128) b4 = *(const float4*)(xb1 + (kt + 1) * 64);
        }
        const unsigned short* A = Ald[kh][buf];
        const unsigned short* Wkt = Wb + (size_t)kt * 12288;
#pragma unroll
        for (int kk = 0; kk < 4; ++kk) {
            bf16x8 af = *(const bf16x8*)(A + aro + (((kk * 2 + g) ^ as) << 3));
            bf16x8 bfr = *(const bf16x8*)(Wkt + kk * 16);
            acc = MFMA32(af, bfr, acc);
        }
        if (kt < 7) {                     // write late (vmcnt waits here)
            *(uint2*)(Ald[kh][buf ^ 1] + wo0) =
                make_uint2(cvt2(a.x, a.y), cvt2(a.z, a.w));
            if (si < 128)
                *(uint2*)(Ald[kh][buf ^ 1] + wo1) =
                    make_uint2(cvt2(b4.x, b4.y), cvt2(b4.z, b4.w));
        }
        __syncthreads();
        buf ^= 1;
    }

    // combine K-halves
    if (kh == 1) {
#pragma unroll
        for (int r = 0; r < 16; r += 4)
            *(float4*)&Osum[ct][l][r] =
                make_float4(acc[r], acc[r + 1], acc[r + 2], acc[r + 3]);
    }
    __syncthreads();
    if (kh == 1) return;
#pragma unroll
    for (int r = 0; r < 16; ++r) acc[r] += Osum[ct][l][r];

    // epilogue (6 waves, kh==0)
    const int cg = ct * 32 + c32;
    const float bias = bias_t[cg];
    const int mat = cg >> 6, cm = cg & 63;
    if (mat == 2) {
        // v chunk-tiled: vt[b][chunk][64 d][32 t]
#pragma unroll
        for (int q4 = 0; q4 < 4; ++q4) {
            const int rowg = rowbase + 8 * q4 + 4 * g;
            const int b = rowg >> 12, tl = rowg & (T_SEQ - 1);
            const int c = tl >> 5, t5 = tl & 31;
            unsigned lo = cvt2(acc[4 * q4 + 0] + bias, acc[4 * q4 + 1] + bias);
            unsigned hi = cvt2(acc[4 * q4 + 2] + bias, acc[4 * q4 + 3] + bias);
            *(uint2*)(vt + (((size_t)b * 128 + c) * 64 + cm) * 32 + t5) =
                make_uint2(lo, hi);
        }
    } else {
        unsigned short* dst = (mat == 0) ? qs : ks;
#pragma unroll
        for (int r = 0; r < 16; ++r) {
            const int rowg = rowbase + (r & 3) + 8 * (r >> 2) + 4 * g;
            dst[(size_t)rowg * 64 + cm] = bf1(acc[r] + bias);
        }
    }
}

// ---------------- kernel 3: causal flash attention ----------------
// Block = one 32-row q-tile. 8 waves split 32-key chunks mod 8.
// S^T = mfma(K, Q); O^T = mfma(V^T, P). Defer-max. V chunk-tiled (4KB/chunk).
__global__ __launch_bounds__(512) void attn_kernel(
        const unsigned short* __restrict__ qs, const unsigned short* __restrict__ ks,
        const unsigned short* __restrict__ vt, float* __restrict__ out) {
    __shared__ float Osh[8][32][66];
    __shared__ float msh[8][32];
    __shared__ float ssh[8][32];

    const int tid = threadIdx.x;
    const int w = tid >> 6, l = tid & 63, g = l >> 5, c32 = l & 31;
    // pair big+small q-tiles onto co-resident blocks (bx, bx+256)
    const int half = blockIdx.x >> 8, idx = blockIdx.x & 255;
    const int b = idx & 3, kk_ = idx >> 2;
    const int jt = half ? kk_ : 127 - kk_;
    const int qbase = jt * 32;

    const unsigned short* qp =
        qs + ((size_t)b * T_SEQ + qbase + c32) * 64 + g * 8;
    bf16x8 qf[4];
#pragma unroll
    for (int t = 0; t < 4; ++t) qf[t] = *(const bf16x8*)(qp + 16 * t);

    const unsigned short* pKc =
        ks + ((size_t)b * T_SEQ + c32) * 64 + g * 8 + (size_t)w * 2048;
    const unsigned short* pVc =
        vt + ((size_t)b * 128 + w) * 2048 + c32 * 32 + g * 8;

    auto loadKV = [&](bf16x8(&kf)[4], bf16x8(&vf)[4]) {
#pragma unroll
        for (int t = 0; t < 4; ++t)
            kf[t] = *(const bf16x8*)(pKc + 16 * t);
#pragma unroll
        for (int mf = 0; mf < 2; ++mf)
#pragma unroll
            for (int kx = 0; kx < 2; ++kx)
                vf[mf * 2 + kx] = *(const bf16x8*)(pVc + mf * 1024 + kx * 16);
        pKc += 8 * 2048;
        pVc += 8 * 2048;
    };

    float m = -INFINITY, ssum = 0.0f;
    f32x16 o0 = zero16(), o1 = zero16();
    const int nch = (jt >= w) ? ((jt - w) >> 3) + 1 : 0;

    bf16x8 ka[4], va[4], kb[4], vb[4];
    if (nch > 0) loadKV(ka, va);

    auto step = [&](bf16x8(&kc)[4], bf16x8(&vc)[4],
                    bf16x8(&kn)[4], bf16x8(&vn)[4], int i) {
        const int c = w + 8 * i;
        if (i + 1 < nch) loadKV(kn, vn);   // prefetch next chunk
        f32x16 s = zero16();
#pragma unroll
        for (int t = 0; t < 4; ++t) s = MFMA32(kc[t], qf[t], s);
        if (c == jt) {   // diagonal chunk: causal mask
#pragma unroll
            for (int r = 0; r < 16; ++r) {
                const int kl = (r & 3) + 8 * (r >> 2) + 4 * g;
                if (kl > c32) s[r] = -1e30f;
            }
        }
        float pm = s[0];
#pragma unroll
        for (int r = 1; r < 16; ++r) pm = fmaxf(pm, s[r]);
        pm = fmaxf(pm, __shfl_xor(pm, 32, 64));
        if (!__all(pm <= m + 8.0f)) {      // defer-max
            const float mn = fmaxf(m, pm);
            const float alpha = exp2f(m - mn);
#pragma unroll
            for (int r = 0; r < 16; ++r) { o0[r] *= alpha; o1[r] *= alpha; }
            ssum *= alpha;
            m = mn;
        }
        float p[16], ps = 0.0f;
#pragma unroll
        for (int r = 0; r < 16; ++r) { p[r] = exp2f(s[r] - m); ps += p[r]; }
        ps += __shfl_xor(ps, 32, 64);
        ssum += ps;
        unsigned c01 = cvt2(p[0], p[1]), c23 = cvt2(p[2], p[3]);
        unsigned c45 = cvt2(p[4], p[5]), c67 = cvt2(p[6], p[7]);
        pswap(c01, c45); pswap(c23, c67);
        unsigned c89 = cvt2(p[8], p[9]), cab = cvt2(p[10], p[11]);
        unsigned ccd = cvt2(p[12], p[13]), cef = cvt2(p[14], p[15]);
        pswap(c89, ccd); pswap(cab, cef);
        uint4v u0; u0[0] = c01; u0[1] = c23; u0[2] = c45; u0[3] = c67;
        uint4v u1; u1[0] = c89; u1[1] = cab; u1[2] = ccd; u1[3] = cef;
        bf16x8 pb0 = __builtin_bit_cast(bf16x8, u0);
        bf16x8 pb1 = __builtin_bit_cast(bf16x8, u1);
        o0 = MFMA32(vc[0], pb0, o0);
        o0 = MFMA32(vc[1], pb1, o0);
        o1 = MFMA32(vc[2], pb0, o1);
        o1 = MFMA32(vc[3], pb1, o1);
    };

    for (int i = 0; i < nch; i += 2) {   // static reg double-buffer
        step(ka, va, kb, vb, i);
        if (i + 1 < nch) step(kb, vb, ka, va, i + 1);
    }

    // ---- combine 8 wave-partials ----
    if (l < 32) { msh[w][l] = m; ssh[w][l] = ssum; }
#pragma unroll
    for (int r = 0; r < 16; ++r) {
        const int dl = (r & 3) + 8 * (r >> 2) + 4 * g;
        Osh[w][c32][dl] = o0[r];
        Osh[w][c32][32 + dl] = o1[r];
    }
    __syncthreads();

    const int qrow = tid >> 4, d0 = (tid & 15) * 4;
    float mw[8], M = -INFINITY;
#pragma unroll
    for (int u = 0; u < 8; ++u) { mw[u] = msh[u][qrow]; M = fmaxf(M, mw[u]); }
    float den = 0.0f, sc[8];
#pragma unroll
    for (int u = 0; u < 8; ++u) { sc[u] = exp2f(mw[u] - M); den += ssh[u][qrow] * sc[u]; }
    const float inv = 1.0f / den;
    float r4[4] = {0.f, 0.f, 0.f, 0.f};
#pragma unroll
    for (int u = 0; u < 8; ++u)
#pragma unroll
        for (int e = 0; e < 4; ++e) r4[e] += Osh[u][qrow][d0 + e] * sc[u];
    float4 o;
    o.x = r4[0] * inv; o.y = r4[1] * inv; o.z = r4[2] * inv; o.w = r4[3] * inv;
    *(float4*)(out + ((size_t)b * T_SEQ + qbase + qrow) * 64 + d0) = o;
}

// ---------------- launch ----------------
extern "C" void kernel_launch(void* const* d_in, const int* in_sizes, int n_in,
                              void* d_out, int out_size, void* d_ws, size_t ws_size,
                              hipStream_t stream) {
    const float* x  = (const float*)d_in[0];
    const float* Wq = (const float*)d_in[1];
    const float* bq = (const float*)d_in[2];
    const float* Wk = (const float*)d_in[3];
    const float* bk = (const float*)d_in[4];
    const float* Wv = (const float*)d_in[5];
    const float* bv = (const float*)d_in[6];
    float* out = (float*)d_out;

    char* ws = (char*)d_ws;
    unsigned short* Wt2    = (unsigned short*)(ws);                 // 384 KB
    float*          bias_t = (float*)(ws + 393216);                 // 768 B
    unsigned short* qsb    = (unsigned short*)(ws + (1u << 20));    // 2 MB
    unsigned short* ksb    = (unsigned short*)(ws + (3u << 20));    // 2 MB
    unsigned short* vtb    = (unsigned short*)(ws + (5u << 20));    // 2 MB

    prep_w<<<48, 256, 0, stream>>>(Wq, Wk, Wv, bq, bk, bv, Wt2, bias_t);
    proj_kernel<<<512, 768, 0, stream>>>(x, Wt2, bias_t, qsb, ksb, vtb);
    attn_kernel<<<512, 512, 0, stream>>>(qsb, ksb, vtb, out);
}

// Round 5
// 76.257 us; speedup vs baseline: 1.5188x; 1.0037x over previous
//
#include <hip/hip_runtime.h>
#include <hip/hip_bf16.h>

// AttentionHead: B=4, T=4096, D=1024, DA=64, scale = 1/96 folded into q.
// prep_w (W -> K-chunked bf16 Wt2) -> proj (LDS-staged MFMA GEMM, 12 waves,
// K-split) -> attn (8-wave split-K flash, chunk-tiled V, balanced q-tiles).

#define T_SEQ 4096

using bf16x8 = __bf16 __attribute__((ext_vector_type(8)));
using f32x16 = float __attribute__((ext_vector_type(16)));
using uint4v = unsigned int __attribute__((ext_vector_type(4)));

// log2(e) / (sqrt(DA) * N_LAYERS): fold softmax scale AND exp->exp2 into q.
static constexpr float QSCALE = 1.4426950408889634f / 96.0f;

// fp32 -> bf16 (RNE) bit math (finite inputs only)
__device__ __forceinline__ unsigned short bf1(float v) {
    unsigned u = __builtin_bit_cast(unsigned, v);
    u += 0x7FFFu + ((u >> 16) & 1u);
    return (unsigned short)(u >> 16);
}
// packed fp32x2 -> bf16x2, single HW instr
__device__ __forceinline__ unsigned cvt2(float lo, float hi) {
    unsigned r;
    asm("v_cvt_pk_bf16_f32 %0, %1, %2" : "=v"(r) : "v"(lo), "v"(hi));
    return r;
}
// v_permlane32_swap: a' = {a.lo32, b.lo32}, b' = {a.hi32, b.hi32}
__device__ __forceinline__ void pswap(unsigned& a, unsigned& b) {
    asm volatile("v_permlane32_swap_b32 %0, %1" : "+v"(a), "+v"(b));
}
__device__ __forceinline__ f32x16 zero16() {
    f32x16 z;
#pragma unroll
    for (int i = 0; i < 16; ++i) z[i] = 0.0f;
    return z;
}
#define MFMA32(a, b, c) __builtin_amdgcn_mfma_f32_32x32x16_bf16(a, b, c, 0, 0, 0)

// ---------------- kernel 1: W -> Wt2[kstep16][192 cols][64 k] bf16 ---------
// 48 blocks: m = bx>>4 (q,k,v), k-tile = bx&15. bias_t[192] fp32.
__global__ __launch_bounds__(256) void prep_w(
        const float* __restrict__ Wq, const float* __restrict__ Wk,
        const float* __restrict__ Wv, const float* __restrict__ bq,
        const float* __restrict__ bk, const float* __restrict__ bv,
        unsigned short* __restrict__ Wt2, float* __restrict__ bias_t) {
    __shared__ float tile[64][65];
    const int tid = threadIdx.x;
    const int m = blockIdx.x >> 4, kt = blockIdx.x & 15, d0 = kt * 64;
    const float* W = (m == 0) ? Wq : (m == 1) ? Wk : Wv;
    const int a = tid & 63, r4 = tid >> 6;
#pragma unroll
    for (int j = 0; j < 16; ++j) {
        const int rr = r4 + 4 * j;
        tile[rr][a] = W[(size_t)(d0 + rr) * 64 + a];   // coalesced 256B
    }
    __syncthreads();
    const float scl = (m == 0) ? QSCALE : 1.0f;
    const int dc = tid & 63, ar = tid >> 6;
#pragma unroll
    for (int j = 0; j < 16; ++j) {
        const int aa = ar + 4 * j;
        Wt2[(size_t)kt * 12288 + (size_t)(m * 64 + aa) * 64 + dc] =
            bf1(tile[dc][aa] * scl);                   // coalesced 128B
    }
    if (kt == 0 && tid < 64) {
        const float* bb = (m == 0) ? bq : (m == 1) ? bk : bv;
        bias_t[m * 64 + tid] = bb[tid] * scl;
    }
}

// ---------------- kernel 2: QKV projection (LDS-staged MFMA GEMM) ----------
// 512 blocks x 768 thr = 12 waves: wave = (ct 0..5, kh 0..1). 32 rows/block.
// A (x rows) staged coalesced f32 -> bf16 -> XOR-swizzled LDS, double-buffered.
// B = Wt2 K-chunk (contiguous 4KB per (ct,kstep)). K-halves combine via LDS.
__global__ __launch_bounds__(768) void proj_kernel(
        const float* __restrict__ x, const unsigned short* __restrict__ Wt2,
        const float* __restrict__ bias_t, unsigned short* __restrict__ qs,
        unsigned short* __restrict__ ks, unsigned short* __restrict__ vt) {
    __shared__ unsigned short Ald[2][2][2048];   // [kh][buf][32 rows x 64 k]
    __shared__ float Osum[6][64][16];            // kh=1 partials

    const int tid = threadIdx.x;
    const int w = tid >> 6, l = tid & 63, g = l >> 5, c32 = l & 31;
    const int ct = w >> 1, kh = w & 1;
    const int rowbase = blockIdx.x * 32;

    // staging: 512 float4 loads per kh-group (384 thr: si<128 do two)
    const int si = ct * 64 + l;
    const int r0 = si >> 4, k40 = si & 15;
    const int i1 = si + 384, r1 = i1 >> 4, k41 = i1 & 15;
    const float* xb0 = x + (size_t)(rowbase + r0) * 1024 + kh * 512 + k40 * 4;
    const float* xb1 = x + (size_t)(rowbase + r1) * 1024 + kh * 512 + k41 * 4;
    const int wo0 = r0 * 64 + (((k40 >> 1) ^ (r0 & 7)) << 3) + (k40 & 1) * 4;
    const int wo1 = r1 * 64 + (((k41 >> 1) ^ (r1 & 7)) << 3) + (k41 & 1) * 4;

    // B pointer: Wt2[kstep][192][64], kstep = kh*8 + kt
    const unsigned short* Wb =
        Wt2 + (size_t)(kh * 8) * 12288 + (size_t)(ct * 32 + c32) * 64 + g * 8;
    const int aro = c32 * 64;            // A-frag row base (ushorts)
    const int as = c32 & 7;              // swizzle key

    f32x16 acc = zero16();

    // prologue: stage kt=0 into buf 0
    {
        float4 a = *(const float4*)(xb0);
        float4 b4;
        if (si < 128) b4 = *(const float4*)(xb1);
        *(uint2*)(Ald[kh][0] + wo0) = make_uint2(cvt2(a.x, a.y), cvt2(a.z, a.w));
        if (si < 128)
            *(uint2*)(Ald[kh][0] + wo1) = make_uint2(cvt2(b4.x, b4.y), cvt2(b4.z, b4.w));
    }
    __syncthreads();

    int buf = 0;
#pragma unroll
    for (int kt = 0; kt < 8; ++kt) {
        float4 a, b4;
        if (kt < 7) {                     // issue next-step loads early
            a = *(const float4*)(xb0 + (kt + 1) * 64);
            if (si < 128) b4 = *(const float4*)(xb1 + (kt + 1) * 64);
        }
        const unsigned short* A = Ald[kh][buf];
        const unsigned short* Wkt = Wb + (size_t)kt * 12288;
#pragma unroll
        for (int kk = 0; kk < 4; ++kk) {
            bf16x8 af = *(const bf16x8*)(A + aro + (((kk * 2 + g) ^ as) << 3));
            bf16x8 bfr = *(const bf16x8*)(Wkt + kk * 16);
            acc = MFMA32(af, bfr, acc);
        }
        if (kt < 7) {                     // write late (vmcnt waits here)
            *(uint2*)(Ald[kh][buf ^ 1] + wo0) =
                make_uint2(cvt2(a.x, a.y), cvt2(a.z, a.w));
            if (si < 128)
                *(uint2*)(Ald[kh][buf ^ 1] + wo1) =
                    make_uint2(cvt2(b4.x, b4.y), cvt2(b4.z, b4.w));
        }
        __syncthreads();
        buf ^= 1;
    }

    // combine K-halves
    if (kh == 1) {
#pragma unroll
        for (int r = 0; r < 16; r += 4)
            *(float4*)&Osum[ct][l][r] =
                make_float4(acc[r], acc[r + 1], acc[r + 2], acc[r + 3]);
    }
    __syncthreads();
    if (kh == 1) return;
#pragma unroll
    for (int r = 0; r < 16; ++r) acc[r] += Osum[ct][l][r];

    // epilogue (6 waves, kh==0)
    const int cg = ct * 32 + c32;
    const float bias = bias_t[cg];
    const int mat = cg >> 6, cm = cg & 63;
    if (mat == 2) {
        // v chunk-tiled: vt[b][chunk][64 d][32 t]
#pragma unroll
        for (int q4 = 0; q4 < 4; ++q4) {
            const int rowg = rowbase + 8 * q4 + 4 * g;
            const int b = rowg >> 12, tl = rowg & (T_SEQ - 1);
            const int c = tl >> 5, t5 = tl & 31;
            unsigned lo = cvt2(acc[4 * q4 + 0] + bias, acc[4 * q4 + 1] + bias);
            unsigned hi = cvt2(acc[4 * q4 + 2] + bias, acc[4 * q4 + 3] + bias);
            *(uint2*)(vt + (((size_t)b * 128 + c) * 64 + cm) * 32 + t5) =
                make_uint2(lo, hi);
        }
    } else {
        unsigned short* dst = (mat == 0) ? qs : ks;
#pragma unroll
        for (int r = 0; r < 16; ++r) {
            const int rowg = rowbase + (r & 3) + 8 * (r >> 2) + 4 * g;
            dst[(size_t)rowg * 64 + cm] = bf1(acc[r] + bias);
        }
    }
}

// ---------------- kernel 3: causal flash attention ----------------
// Block = one 32-row q-tile. 8 waves split 32-key chunks mod 8.
// S^T = mfma(K, Q); O^T = mfma(V^T, P). Defer-max. V chunk-tiled (4KB/chunk).
__global__ __launch_bounds__(512) void attn_kernel(
        const unsigned short* __restrict__ qs, const unsigned short* __restrict__ ks,
        const unsigned short* __restrict__ vt, float* __restrict__ out) {
    __shared__ float Osh[8][32][66];
    __shared__ float msh[8][32];
    __shared__ float ssh[8][32];

    const int tid = threadIdx.x;
    const int w = tid >> 6, l = tid & 63, g = l >> 5, c32 = l & 31;
    // pair big+small q-tiles onto co-resident blocks (bx, bx+256)
    const int half = blockIdx.x >> 8, idx = blockIdx.x & 255;
    const int b = idx & 3, kk_ = idx >> 2;
    const int jt = half ? kk_ : 127 - kk_;
    const int qbase = jt * 32;

    const unsigned short* qp =
        qs + ((size_t)b * T_SEQ + qbase + c32) * 64 + g * 8;
    bf16x8 qf[4];
#pragma unroll
    for (int t = 0; t < 4; ++t) qf[t] = *(const bf16x8*)(qp + 16 * t);

    const unsigned short* pKc =
        ks + ((size_t)b * T_SEQ + c32) * 64 + g * 8 + (size_t)w * 2048;
    const unsigned short* pVc =
        vt + ((size_t)b * 128 + w) * 2048 + c32 * 32 + g * 8;

    auto loadKV = [&](bf16x8(&kf)[4], bf16x8(&vf)[4]) {
#pragma unroll
        for (int t = 0; t < 4; ++t)
            kf[t] = *(const bf16x8*)(pKc + 16 * t);
#pragma unroll
        for (int mf = 0; mf < 2; ++mf)
#pragma unroll
            for (int kx = 0; kx < 2; ++kx)
                vf[mf * 2 + kx] = *(const bf16x8*)(pVc + mf * 1024 + kx * 16);
        pKc += 8 * 2048;
        pVc += 8 * 2048;
    };

    float m = -INFINITY, ssum = 0.0f;
    f32x16 o0 = zero16(), o1 = zero16();
    const int nch = (jt >= w) ? ((jt - w) >> 3) + 1 : 0;

    bf16x8 ka[4], va[4], kb[4], vb[4];
    if (nch > 0) loadKV(ka, va);

    auto step = [&](bf16x8(&kc)[4], bf16x8(&vc)[4],
                    bf16x8(&kn)[4], bf16x8(&vn)[4], int i) {
        const int c = w + 8 * i;
        if (i + 1 < nch) loadKV(kn, vn);   // prefetch next chunk
        f32x16 s = zero16();
#pragma unroll
        for (int t = 0; t < 4; ++t) s = MFMA32(kc[t], qf[t], s);
        if (c == jt) {   // diagonal chunk: causal mask
#pragma unroll
            for (int r = 0; r < 16; ++r) {
                const int kl = (r & 3) + 8 * (r >> 2) + 4 * g;
                if (kl > c32) s[r] = -1e30f;
            }
        }
        float pm = s[0];
#pragma unroll
        for (int r = 1; r < 16; ++r) pm = fmaxf(pm, s[r]);
        pm = fmaxf(pm, __shfl_xor(pm, 32, 64));
        if (!__all(pm <= m + 8.0f)) {      // defer-max
            const float mn = fmaxf(m, pm);
            const float alpha = exp2f(m - mn);
#pragma unroll
            for (int r = 0; r < 16; ++r) { o0[r] *= alpha; o1[r] *= alpha; }
            ssum *= alpha;
            m = mn;
        }
        float p[16], ps = 0.0f;
#pragma unroll
        for (int r = 0; r < 16; ++r) { p[r] = exp2f(s[r] - m); ps += p[r]; }
        ps += __shfl_xor(ps, 32, 64);
        ssum += ps;
        unsigned c01 = cvt2(p[0], p[1]), c23 = cvt2(p[2], p[3]);
        unsigned c45 = cvt2(p[4], p[5]), c67 = cvt2(p[6], p[7]);
        pswap(c01, c45); pswap(c23, c67);
        unsigned c89 = cvt2(p[8], p[9]), cab = cvt2(p[10], p[11]);
        unsigned ccd = cvt2(p[12], p[13]), cef = cvt2(p[14], p[15]);
        pswap(c89, ccd); pswap(cab, cef);
        uint4v u0; u0[0] = c01; u0[1] = c23; u0[2] = c45; u0[3] = c67;
        uint4v u1; u1[0] = c89; u1[1] = cab; u1[2] = ccd; u1[3] = cef;
        bf16x8 pb0 = __builtin_bit_cast(bf16x8, u0);
        bf16x8 pb1 = __builtin_bit_cast(bf16x8, u1);
        o0 = MFMA32(vc[0], pb0, o0);
        o0 = MFMA32(vc[1], pb1, o0);
        o1 = MFMA32(vc[2], pb0, o1);
        o1 = MFMA32(vc[3], pb1, o1);
    };

    for (int i = 0; i < nch; i += 2) {   // static reg double-buffer
        step(ka, va, kb, vb, i);
        if (i + 1 < nch) step(kb, vb, ka, va, i + 1);
    }

    // ---- combine 8 wave-partials ----
    if (l < 32) { msh[w][l] = m; ssh[w][l] = ssum; }
#pragma unroll
    for (int r = 0; r < 16; ++r) {
        const int dl = (r & 3) + 8 * (r >> 2) + 4 * g;
        Osh[w][c32][dl] = o0[r];
        Osh[w][c32][32 + dl] = o1[r];
    }
    __syncthreads();

    const int qrow = tid >> 4, d0 = (tid & 15) * 4;
    float mw[8], M = -INFINITY;
#pragma unroll
    for (int u = 0; u < 8; ++u) { mw[u] = msh[u][qrow]; M = fmaxf(M, mw[u]); }
    float den = 0.0f, sc[8];
#pragma unroll
    for (int u = 0; u < 8; ++u) { sc[u] = exp2f(mw[u] - M); den += ssh[u][qrow] * sc[u]; }
    const float inv = 1.0f / den;
    float r4[4] = {0.f, 0.f, 0.f, 0.f};
#pragma unroll
    for (int u = 0; u < 8; ++u)
#pragma unroll
        for (int e = 0; e < 4; ++e) r4[e] += Osh[u][qrow][d0 + e] * sc[u];
    float4 o;
    o.x = r4[0] * inv; o.y = r4[1] * inv; o.z = r4[2] * inv; o.w = r4[3] * inv;
    *(float4*)(out + ((size_t)b * T_SEQ + qbase + qrow) * 64 + d0) = o;
}

// ---------------- launch ----------------
extern "C" void kernel_launch(void* const* d_in, const int* in_sizes, int n_in,
                              void* d_out, int out_size, void* d_ws, size_t ws_size,
                              hipStream_t stream) {
    const float* x  = (const float*)d_in[0];
    const float* Wq = (const float*)d_in[1];
    const float* bq = (const float*)d_in[2];
    const float* Wk = (const float*)d_in[3];
    const float* bk = (const float*)d_in[4];
    const float* Wv = (const float*)d_in[5];
    const float* bv = (const float*)d_in[6];
    float* out = (float*)d_out;

    char* ws = (char*)d_ws;
    unsigned short* Wt2    = (unsigned short*)(ws);                 // 384 KB
    float*          bias_t = (float*)(ws + 393216);                 // 768 B
    unsigned short* qsb    = (unsigned short*)(ws + (1u << 20));    // 2 MB
    unsigned short* ksb    = (unsigned short*)(ws + (3u << 20));    // 2 MB
    unsigned short* vtb    = (unsigned short*)(ws + (5u << 20));    // 2 MB

    prep_w<<<48, 256, 0, stream>>>(Wq, Wk, Wv, bq, bk, bv, Wt2, bias_t);
    proj_kernel<<<512, 768, 0, stream>>>(x, Wt2, bias_t, qsb, ksb, vtb);
    attn_kernel<<<512, 512, 0, stream>>>(qsb, ksb, vtb, out);
}